// Round 8
// baseline (770.196 us; speedup 1.0000x reference)
//
#include <hip/hip_runtime.h>
#include <hip/hip_fp16.h>
#include <cstdint>
#include <cstddef>

static constexpr int NN    = 100000;
static constexpr int NE    = 1600000;
static constexpr int IN_C  = 128;
static constexpr int HID_C = 64;
static constexpr int OUT_C = 32;

// Bucketed scatter geometry: 256 rows/bucket, 8 sub-buckets (XCD-affinity via
// blockIdx&7), fixed slot capacity (Binomial(200K, 1/391): mean 512, sigma 23;
// cap 768 is z~11 -- deterministically safe for this fixed graph).
static constexpr int NB   = (NN + 255) >> 8;   // 391
static constexpr int SUBS = 8;
static constexpr int CAP  = 768;

static inline int cdiv(int a, int b) { return (a + b - 1) / b; }

__global__ void deg_kernel(const int* __restrict__ row, float* __restrict__ deg, int E) {
    int i = blockIdx.x * 256 + threadIdx.x;
    if (i < E) atomicAdd(&deg[row[i]], 1.0f);
}

__global__ void dis_kernel(const float* __restrict__ deg, float* __restrict__ dis, int n) {
    int i = blockIdx.x * 256 + threadIdx.x;
    if (i < n) {
        float d = deg[i];
        dis[i] = d > 0.0f ? rsqrtf(fmaxf(d, 1.0f)) : 0.0f;
    }
}

// Block-exclusive scan of (int)deg into row_start; per-block totals into partials.
__global__ void scan1_kernel(const float* __restrict__ deg, int* __restrict__ row_start,
                             int* __restrict__ partials, int n) {
    __shared__ int tmp[256];
    int t = threadIdx.x;
    int i = blockIdx.x * 256 + t;
    int v = (i < n) ? (int)deg[i] : 0;
    tmp[t] = v;
    __syncthreads();
    for (int off = 1; off < 256; off <<= 1) {
        int add = (t >= off) ? tmp[t - off] : 0;
        __syncthreads();
        tmp[t] += add;
        __syncthreads();
    }
    if (i < n) row_start[i] = tmp[t] - v;
    if (t == 255) partials[blockIdx.x] = tmp[t];
}

__global__ void scan2_kernel(int* __restrict__ partials, int nparts) {
    __shared__ int tmp[512];
    int t = threadIdx.x;
    int v = (t < nparts) ? partials[t] : 0;
    tmp[t] = v;
    __syncthreads();
    for (int off = 1; off < 512; off <<= 1) {
        int add = (t >= off) ? tmp[t - off] : 0;
        __syncthreads();
        tmp[t] += add;
        __syncthreads();
    }
    if (t < nparts) partials[t] = tmp[t] - v;
}

__global__ void scan3_kernel(int* __restrict__ row_start, const int* __restrict__ partials,
                             int n, int total) {
    int i = blockIdx.x * 256 + threadIdx.x;
    if (i < n) row_start[i] += partials[blockIdx.x];
    if (i == 0) row_start[n] = total;
}

// Phase 1: append (row&255, col) packed u32 into per-(bucket, blockIdx&7) slots.
// Sub-bucket keyed by blockIdx&7 keeps each append stream on (mostly) one XCD,
// so staged lines fill before writeback. Correctness independent of mapping.
__global__ void scatter_p1(const int* __restrict__ row, const int* __restrict__ col,
                           int* __restrict__ cur, unsigned* __restrict__ staging, int E) {
    int i = blockIdx.x * 256 + threadIdx.x;
    if (i >= E) return;
    int r = row[i], c = col[i];
    int slot = ((r >> 8) << 3) | (blockIdx.x & 7);
    int pos = atomicAdd(&cur[slot], 1);
    if (pos < CAP) staging[(size_t)slot * CAP + pos] = ((unsigned)(r & 255) << 17) | (unsigned)c;
}

// Phase 2: one block per bucket; LDS cursors seeded from row_start; writes
// csr_col into the bucket's block-exclusive output range (lines written once).
__global__ __launch_bounds__(256) void scatter_p2(
        const int* __restrict__ row_start, const int* __restrict__ cur,
        const unsigned* __restrict__ staging, int* __restrict__ csr_col, int n) {
    __shared__ int lcur[256];
    int b = blockIdx.x;
    int r = (b << 8) + threadIdx.x;
    lcur[threadIdx.x] = (r < n) ? row_start[r] : 0;
    __syncthreads();
    for (int sub = 0; sub < SUBS; ++sub) {
        int slot = (b << 3) | sub;
        int cnt = min(cur[slot], CAP);
        const unsigned* seg = staging + (size_t)slot * CAP;
        for (int i = threadIdx.x; i < cnt; i += 256) {
            unsigned u = seg[i];
            int lr = (int)(u >> 17);
            int c  = (int)(u & 0x1FFFF);
            int pos = atomicAdd(&lcur[lr], 1);
            csr_col[pos] = c;
        }
    }
}

// A layout: A[c][kk*Cout + o], where A0=W0-W2, A1=W1-3W3, A2=2W2, A3=4W3.
__global__ void wtrans_kernel(const float* __restrict__ W, float* __restrict__ A,
                              int Cin, int Cout) {
    int idx = blockIdx.x * 256 + threadIdx.x;
    int total = Cin * 4 * Cout;
    if (idx >= total) return;
    int o  = idx % Cout;
    int kk = (idx / Cout) & 3;
    int c  = idx / (4 * Cout);
    size_t s = (size_t)Cin * Cout;
    float v;
    if (kk == 0)      v = W[0 * s + (size_t)c * Cout + o] - W[2 * s + (size_t)c * Cout + o];
    else if (kk == 1) v = W[1 * s + (size_t)c * Cout + o] - 3.0f * W[3 * s + (size_t)c * Cout + o];
    else if (kk == 2) v = 2.0f * W[2 * s + (size_t)c * Cout + o];
    else              v = 4.0f * W[3 * s + (size_t)c * Cout + o];
    A[idx] = v;   // idx == c*(4*Cout) + kk*Cout + o
}

// Y[n..][M] = X[n..][Kdim] @ A[Kdim][M], output __half.
// Columns >= c3b (the Z3 slice) are pre-scaled by dis[row] so the following
// propagation gathers need no per-edge weight.
// 64x64 tile / block, 256 threads, 4x4 per thread, k-major LDS tiles.
template <typename TI>
__global__ __launch_bounds__(256) void matmul64_kernel(
        const TI* __restrict__ X, const float* __restrict__ A,
        __half* __restrict__ Y, const float* __restrict__ dis,
        int n, int Kdim, int M, int c3b) {
    __shared__ float xs[64][68];
    __shared__ float ws[64][68];
    int row0 = blockIdx.x * 64, col0 = blockIdx.y * 64;
    int tid = threadIdx.x;
    int tr = tid >> 4;    // 0..15 row group
    int tc = tid & 15;    // 0..15 col group
    float acc[4][4] = {};
    for (int kt = 0; kt < Kdim; kt += 64) {
#pragma unroll
        for (int l = 0; l < 4; ++l) {
            int idx = (tid + l * 256) * 4;   // element index in 64x64 tile
            int r = idx >> 6, c = idx & 63;
            float4 v = make_float4(0.f, 0.f, 0.f, 0.f);
            int gr = row0 + r;
            if (gr < n) {
                if constexpr (sizeof(TI) == 4) {
                    v = *(const float4*)((const float*)X + (size_t)gr * Kdim + kt + c);
                } else {
                    const __half2* q = (const __half2*)((const __half*)X + (size_t)gr * Kdim + kt + c);
                    float2 f0 = __half22float2(q[0]);
                    float2 f1 = __half22float2(q[1]);
                    v = make_float4(f0.x, f0.y, f1.x, f1.y);
                }
            }
            xs[c + 0][r] = v.x; xs[c + 1][r] = v.y; xs[c + 2][r] = v.z; xs[c + 3][r] = v.w;
            int k = r;
            float4 w4 = *(const float4*)(A + (size_t)(kt + k) * M + col0 + c);
            *(float4*)&ws[k][c] = w4;
        }
        __syncthreads();
#pragma unroll
        for (int k = 0; k < 64; ++k) {
            float4 xa = *(const float4*)&xs[k][tr * 4];
            float4 wb = *(const float4*)&ws[k][tc * 4];
            float xv[4] = {xa.x, xa.y, xa.z, xa.w};
            float wv[4] = {wb.x, wb.y, wb.z, wb.w};
#pragma unroll
            for (int i = 0; i < 4; ++i)
#pragma unroll
                for (int j = 0; j < 4; ++j)
                    acc[i][j] = fmaf(xv[i], wv[j], acc[i][j]);
        }
        __syncthreads();
    }
    bool z3 = (col0 + tc * 4) >= c3b;   // c3b is 4-aligned; all 4 cols share it
#pragma unroll
    for (int i = 0; i < 4; ++i) {
        int gr = row0 + tr * 4 + i;
        if (gr < n) {
            float s = z3 ? dis[gr] : 1.0f;
            union { uint2 u; __half2 h[2]; } pk;
            pk.h[0] = __floats2half2_rn(acc[i][0] * s, acc[i][1] * s);
            pk.h[1] = __floats2half2_rn(acc[i][2] * s, acc[i][3] * s);
            *(uint2*)(Y + (size_t)gr * M + col0 + tc * 4) = pk.u;
        }
    }
}

// out[node,:] = Zadd[node,:] - dis[node] * sum_e Ssrc[col_e,:]  (+bias, relu, lsm)
// Ssrc rows are pre-scaled by dis at their producer, so no per-edge weight.
// If PRESCALE, the stored value is dis[node]*v (feeding the next propagation).
// Edge loop unrolled 8-deep: 8 scalar col loads then 8 independent gathers in
// flight per wave (latency-bound regime; round-1 showed VALUBusy 14%).
template <int C, bool RELU, bool BIAS, bool LSM, bool PRESCALE, typename TO>
__global__ __launch_bounds__(256) void prop_kernel(
        const int* __restrict__ row_start,
        const int* __restrict__ csr_col,
        const float* __restrict__ dis,
        const __half* __restrict__ Ssrc, int ld_src,
        const __half* __restrict__ Zadd, int ld_add,
        const float* __restrict__ bias,
        TO* __restrict__ out, int ld_out, int n) {
    constexpr int NPB = 256 / C;
    int g    = threadIdx.x / C;
    int lane = threadIdx.x % C;
    int node = blockIdx.x * NPB + g;
    if (node >= n) return;
    int s = row_start[node], e = row_start[node + 1];
    if (C == 64) {   // wave-uniform bounds -> scalar loads for col indices
        s = __builtin_amdgcn_readfirstlane(s);
        e = __builtin_amdgcn_readfirstlane(e);
    }
    float dn = dis[node];
    float acc = 0.0f;
    int i = s;
    for (; i + 8 <= e; i += 8) {
        int cc[8];
#pragma unroll
        for (int u = 0; u < 8; ++u) cc[u] = csr_col[i + u];
        float vv[8];
#pragma unroll
        for (int u = 0; u < 8; ++u) vv[u] = __half2float(Ssrc[(size_t)cc[u] * ld_src + lane]);
        acc += ((vv[0] + vv[1]) + (vv[2] + vv[3])) + ((vv[4] + vv[5]) + (vv[6] + vv[7]));
    }
    for (; i < e; ++i)
        acc += __half2float(Ssrc[(size_t)csr_col[i] * ld_src + lane]);

    float v = fmaf(-dn, acc, __half2float(Zadd[(size_t)node * ld_add + lane]));
    if (BIAS) v += bias[lane];
    if (RELU) v = fmaxf(v, 0.0f);
    if (LSM) {
        float m = v;
#pragma unroll
        for (int off = 16; off > 0; off >>= 1) m = fmaxf(m, __shfl_xor(m, off, 32));
        float ex = __expf(v - m);
        float sum = ex;
#pragma unroll
        for (int off = 16; off > 0; off >>= 1) sum += __shfl_xor(sum, off, 32);
        v = (v - m) - __logf(sum);
    }
    if (PRESCALE) v *= dn;
    if constexpr (sizeof(TO) == 2) {
        out[(size_t)node * ld_out + lane] = (TO)__float2half_rn(v);
    } else {
        out[(size_t)node * ld_out + lane] = v;
    }
}

extern "C" void kernel_launch(void* const* d_in, const int* in_sizes, int n_in,
                              void* d_out, int out_size, void* d_ws, size_t ws_size,
                              hipStream_t stream) {
    const float* x  = (const float*)d_in[0];
    const int*   ei = (const int*)d_in[1];
    const float* W1 = (const float*)d_in[2];
    const float* b1 = (const float*)d_in[3];
    const float* W2 = (const float*)d_in[4];
    const float* b2 = (const float*)d_in[5];
    float* out = (float*)d_out;

    const int* row = ei;
    const int* col = ei + NE;

    char* p = (char*)d_ws;
    auto alloc = [&](size_t bytes) {
        char* q = p;
        p += (bytes + 255) & ~(size_t)255;
        return q;
    };
    float*  deg       = (float*)alloc((size_t)NN * 4);
    float*  dis       = (float*)alloc((size_t)NN * 4);
    int*    row_start = (int*)alloc((size_t)(NN + 1) * 4);
    int*    p1cur     = (int*)alloc((size_t)NB * SUBS * 4);
    int*    partials  = (int*)alloc(512 * 4);
    int*    csr_col   = (int*)alloc((size_t)NE * 4);
    float*  A1        = (float*)alloc((size_t)IN_C * 4 * HID_C * 4);
    float*  A2        = (float*)alloc((size_t)HID_C * 4 * OUT_C * 4);
    __half* ZZ        = (__half*)alloc((size_t)NN * 256 * 2);  // layer1 Z; reused layer2
    __half* Sa        = (__half*)alloc((size_t)NN * 64 * 2);
    __half* Sb        = (__half*)alloc((size_t)NN * 64 * 2);
    __half* h         = (__half*)alloc((size_t)NN * 64 * 2);

    // Staging (9.6 MB) lives in ZZ, which is dead until matmul1 writes it.
    unsigned* staging = (unsigned*)ZZ;

    hipMemsetAsync(deg, 0, (size_t)NN * 4, stream);
    hipMemsetAsync(p1cur, 0, (size_t)NB * SUBS * 4, stream);
    deg_kernel<<<cdiv(NE, 256), 256, 0, stream>>>(row, deg, NE);
    dis_kernel<<<cdiv(NN, 256), 256, 0, stream>>>(deg, dis, NN);
    scan1_kernel<<<cdiv(NN, 256), 256, 0, stream>>>(deg, row_start, partials, NN);
    scan2_kernel<<<1, 512, 0, stream>>>(partials, cdiv(NN, 256));
    scan3_kernel<<<cdiv(NN, 256), 256, 0, stream>>>(row_start, partials, NN, NE);
    scatter_p1<<<cdiv(NE, 256), 256, 0, stream>>>(row, col, p1cur, staging, NE);
    scatter_p2<<<NB, 256, 0, stream>>>(row_start, p1cur, staging, csr_col, NN);

    wtrans_kernel<<<cdiv(IN_C * 4 * HID_C, 256), 256, 0, stream>>>(W1, A1, IN_C, HID_C);
    wtrans_kernel<<<cdiv(HID_C * 4 * OUT_C, 256), 256, 0, stream>>>(W2, A2, HID_C, OUT_C);

    // Layer 1: ZZ[N,256] = x @ A1 (Z3 slice pre-scaled by dis), Horner props C=64.
    {
        dim3 g1(cdiv(NN, 64), 4);
        matmul64_kernel<float><<<g1, 256, 0, stream>>>(x, A1, ZZ, dis, NN, IN_C, 256, 3 * HID_C);
    }
    prop_kernel<64, false, false, false, true,  __half><<<cdiv(NN, 4), 256, 0, stream>>>(
        row_start, csr_col, dis, ZZ + 3 * 64, 256, ZZ + 2 * 64, 256, nullptr, Sa, 64, NN);
    prop_kernel<64, false, false, false, true,  __half><<<cdiv(NN, 4), 256, 0, stream>>>(
        row_start, csr_col, dis, Sa, 64, ZZ + 1 * 64, 256, nullptr, Sb, 64, NN);
    prop_kernel<64, true,  true,  false, false, __half><<<cdiv(NN, 4), 256, 0, stream>>>(
        row_start, csr_col, dis, Sb, 64, ZZ + 0, 256, b1, h, 64, NN);

    // Layer 2: ZZ[N,128] = h @ A2, Horner props C=32, fused log_softmax.
    {
        dim3 g2(cdiv(NN, 64), 2);
        matmul64_kernel<__half><<<g2, 256, 0, stream>>>(h, A2, ZZ, dis, NN, HID_C, 128, 3 * OUT_C);
    }
    prop_kernel<32, false, false, false, true,  __half><<<cdiv(NN, 8), 256, 0, stream>>>(
        row_start, csr_col, dis, ZZ + 3 * 32, 128, ZZ + 2 * 32, 128, nullptr, Sa, 32, NN);
    prop_kernel<32, false, false, false, true,  __half><<<cdiv(NN, 8), 256, 0, stream>>>(
        row_start, csr_col, dis, Sa, 32, ZZ + 1 * 32, 128, nullptr, Sb, 32, NN);
    prop_kernel<32, false, true,  true,  false, float><<<cdiv(NN, 8), 256, 0, stream>>>(
        row_start, csr_col, dis, Sb, 32, ZZ + 0, 128, b2, out, 32, NN);
}

// Round 9
// 645.326 us; speedup vs baseline: 1.1935x; 1.1935x over previous
//
#include <hip/hip_runtime.h>
#include <hip/hip_fp16.h>
#include <cstdint>
#include <cstddef>

static constexpr int NN    = 100000;
static constexpr int NE    = 1600000;
static constexpr int IN_C  = 128;
static constexpr int HID_C = 64;
static constexpr int OUT_C = 32;

// LDS-binned scatter geometry: coarse bucket = row>>10 (1024 rows/bucket).
// Phase A bins 4096 edges/block into 98 LDS bins (cap 96: mean 41.9, sigma 6.4,
// Chernoff tail ~3e-7 across all bins -- AND overflow falls back to a correct
// global-atomic append, so caps are perf-only). Phase B: one block per bucket,
// LDS cursors, csr writes confined to the bucket's 131KB L2-resident range.
static constexpr int NBKT = (NN + 1023) >> 10;   // 98
static constexpr int LCAP = 96;                  // LDS bin capacity
static constexpr int GCAP = 18432;               // global bucket cap (mean 16384 + 16 sigma)
static constexpr int EPB  = 4096;                // edges per phase-A block

static inline int cdiv(int a, int b) { return (a + b - 1) / b; }

__global__ void deg_kernel(const int* __restrict__ row, float* __restrict__ deg, int E) {
    int i = blockIdx.x * 256 + threadIdx.x;
    if (i < E) atomicAdd(&deg[row[i]], 1.0f);
}

__global__ void dis_kernel(const float* __restrict__ deg, float* __restrict__ dis, int n) {
    int i = blockIdx.x * 256 + threadIdx.x;
    if (i < n) {
        float d = deg[i];
        dis[i] = d > 0.0f ? rsqrtf(fmaxf(d, 1.0f)) : 0.0f;
    }
}

// Block-exclusive scan of (int)deg into row_start; per-block totals into partials.
__global__ void scan1_kernel(const float* __restrict__ deg, int* __restrict__ row_start,
                             int* __restrict__ partials, int n) {
    __shared__ int tmp[256];
    int t = threadIdx.x;
    int i = blockIdx.x * 256 + t;
    int v = (i < n) ? (int)deg[i] : 0;
    tmp[t] = v;
    __syncthreads();
    for (int off = 1; off < 256; off <<= 1) {
        int add = (t >= off) ? tmp[t - off] : 0;
        __syncthreads();
        tmp[t] += add;
        __syncthreads();
    }
    if (i < n) row_start[i] = tmp[t] - v;
    if (t == 255) partials[blockIdx.x] = tmp[t];
}

__global__ void scan2_kernel(int* __restrict__ partials, int nparts) {
    __shared__ int tmp[512];
    int t = threadIdx.x;
    int v = (t < nparts) ? partials[t] : 0;
    tmp[t] = v;
    __syncthreads();
    for (int off = 1; off < 512; off <<= 1) {
        int add = (t >= off) ? tmp[t - off] : 0;
        __syncthreads();
        tmp[t] += add;
        __syncthreads();
    }
    if (t < nparts) partials[t] = tmp[t] - v;
}

__global__ void scan3_kernel(int* __restrict__ row_start, const int* __restrict__ partials,
                             int n, int total) {
    int i = blockIdx.x * 256 + threadIdx.x;
    if (i < n) row_start[i] += partials[blockIdx.x];
    if (i == 0) row_start[n] = total;
}

// Phase A: LDS-bin 4096 edges by row>>10, then per-bin global reservation +
// coalesced flush. Pack = ((row & 1023) << 17) | col  (10 + 17 bits).
__global__ __launch_bounds__(256) void scatter_p1(
        const int* __restrict__ row, const int* __restrict__ col,
        int* __restrict__ gcur, unsigned* __restrict__ staging, int E) {
    __shared__ unsigned bins[NBKT][LCAP];
    __shared__ int bcnt[NBKT];
    __shared__ int bbase[NBKT];
    int tid = threadIdx.x;
    for (int b = tid; b < NBKT; b += 256) bcnt[b] = 0;
    __syncthreads();
    int base = blockIdx.x * EPB;
#pragma unroll
    for (int rep = 0; rep < 4; ++rep) {
        int i = base + rep * 1024 + tid * 4;
        if (i < E) {   // E % 4 == 0 and i % 4 == 0, so i < E implies i+4 <= E
            int4 r4 = *(const int4*)(row + i);
            int4 c4 = *(const int4*)(col + i);
            int rr[4] = {r4.x, r4.y, r4.z, r4.w};
            int cc[4] = {c4.x, c4.y, c4.z, c4.w};
#pragma unroll
            for (int u = 0; u < 4; ++u) {
                int bin = rr[u] >> 10;
                unsigned pk = ((unsigned)(rr[u] & 1023) << 17) | (unsigned)cc[u];
                int pos = atomicAdd(&bcnt[bin], 1);
                if (pos < LCAP) {
                    bins[bin][pos] = pk;
                } else {   // rare overflow: correct global fallback
                    int gp = atomicAdd(&gcur[bin], 1);
                    if (gp < GCAP) staging[(size_t)bin * GCAP + gp] = pk;
                }
            }
        }
    }
    __syncthreads();
    if (tid < NBKT) {
        int cnt = min(bcnt[tid], LCAP);
        bbase[tid] = atomicAdd(&gcur[tid], cnt);
    }
    __syncthreads();
    int wv = tid >> 6, ln = tid & 63;
    for (int b = wv; b < NBKT; b += 4) {
        int cnt = min(bcnt[b], LCAP);
        int gb  = bbase[b];
        for (int j = ln; j < cnt; j += 64)
            staging[(size_t)b * GCAP + gb + j] = bins[b][j];
    }
}

// Phase B: one block per bucket; LDS cursors for 1024 rows; csr_col writes land
// in the bucket's block-exclusive ~131KB range (L2-resident, lines fill fully).
__global__ __launch_bounds__(512) void scatter_p2(
        const int* __restrict__ row_start, const int* __restrict__ gcur,
        const unsigned* __restrict__ staging, int* __restrict__ csr_col, int n) {
    __shared__ int lcur[1024];
    int b = blockIdx.x;
    int r0 = b << 10;
    for (int t = threadIdx.x; t < 1024; t += 512) {
        int r = r0 + t;
        lcur[t] = (r < n) ? row_start[r] : 0;
    }
    __syncthreads();
    int cnt = min(gcur[b], GCAP);
    const unsigned* seg = staging + (size_t)b * GCAP;
    for (int j = threadIdx.x; j < cnt; j += 512) {
        unsigned u = seg[j];
        int lr = (int)(u >> 17);
        int c  = (int)(u & 0x1FFFF);
        int pos = atomicAdd(&lcur[lr], 1);
        csr_col[pos] = c;
    }
}

// A layout: A[c][kk*Cout + o], where A0=W0-W2, A1=W1-3W3, A2=2W2, A3=4W3.
__global__ void wtrans_kernel(const float* __restrict__ W, float* __restrict__ A,
                              int Cin, int Cout) {
    int idx = blockIdx.x * 256 + threadIdx.x;
    int total = Cin * 4 * Cout;
    if (idx >= total) return;
    int o  = idx % Cout;
    int kk = (idx / Cout) & 3;
    int c  = idx / (4 * Cout);
    size_t s = (size_t)Cin * Cout;
    float v;
    if (kk == 0)      v = W[0 * s + (size_t)c * Cout + o] - W[2 * s + (size_t)c * Cout + o];
    else if (kk == 1) v = W[1 * s + (size_t)c * Cout + o] - 3.0f * W[3 * s + (size_t)c * Cout + o];
    else if (kk == 2) v = 2.0f * W[2 * s + (size_t)c * Cout + o];
    else              v = 4.0f * W[3 * s + (size_t)c * Cout + o];
    A[idx] = v;   // idx == c*(4*Cout) + kk*Cout + o
}

// Y[n..][M] = X[n..][Kdim] @ A[Kdim][M], output __half.
// Columns >= c3b (the Z3 slice) are pre-scaled by dis[row] so the following
// propagation gathers need no per-edge weight.
// 64x64 tile / block, 256 threads, 4x4 per thread, k-major LDS tiles.
template <typename TI>
__global__ __launch_bounds__(256) void matmul64_kernel(
        const TI* __restrict__ X, const float* __restrict__ A,
        __half* __restrict__ Y, const float* __restrict__ dis,
        int n, int Kdim, int M, int c3b) {
    __shared__ float xs[64][68];
    __shared__ float ws[64][68];
    int row0 = blockIdx.x * 64, col0 = blockIdx.y * 64;
    int tid = threadIdx.x;
    int tr = tid >> 4;    // 0..15 row group
    int tc = tid & 15;    // 0..15 col group
    float acc[4][4] = {};
    for (int kt = 0; kt < Kdim; kt += 64) {
#pragma unroll
        for (int l = 0; l < 4; ++l) {
            int idx = (tid + l * 256) * 4;   // element index in 64x64 tile
            int r = idx >> 6, c = idx & 63;
            float4 v = make_float4(0.f, 0.f, 0.f, 0.f);
            int gr = row0 + r;
            if (gr < n) {
                if constexpr (sizeof(TI) == 4) {
                    v = *(const float4*)((const float*)X + (size_t)gr * Kdim + kt + c);
                } else {
                    const __half2* q = (const __half2*)((const __half*)X + (size_t)gr * Kdim + kt + c);
                    float2 f0 = __half22float2(q[0]);
                    float2 f1 = __half22float2(q[1]);
                    v = make_float4(f0.x, f0.y, f1.x, f1.y);
                }
            }
            xs[c + 0][r] = v.x; xs[c + 1][r] = v.y; xs[c + 2][r] = v.z; xs[c + 3][r] = v.w;
            int k = r;
            float4 w4 = *(const float4*)(A + (size_t)(kt + k) * M + col0 + c);
            *(float4*)&ws[k][c] = w4;
        }
        __syncthreads();
#pragma unroll
        for (int k = 0; k < 64; ++k) {
            float4 xa = *(const float4*)&xs[k][tr * 4];
            float4 wb = *(const float4*)&ws[k][tc * 4];
            float xv[4] = {xa.x, xa.y, xa.z, xa.w};
            float wv[4] = {wb.x, wb.y, wb.z, wb.w};
#pragma unroll
            for (int i = 0; i < 4; ++i)
#pragma unroll
                for (int j = 0; j < 4; ++j)
                    acc[i][j] = fmaf(xv[i], wv[j], acc[i][j]);
        }
        __syncthreads();
    }
    bool z3 = (col0 + tc * 4) >= c3b;   // c3b is 4-aligned; all 4 cols share it
#pragma unroll
    for (int i = 0; i < 4; ++i) {
        int gr = row0 + tr * 4 + i;
        if (gr < n) {
            float s = z3 ? dis[gr] : 1.0f;
            union { uint2 u; __half2 h[2]; } pk;
            pk.h[0] = __floats2half2_rn(acc[i][0] * s, acc[i][1] * s);
            pk.h[1] = __floats2half2_rn(acc[i][2] * s, acc[i][3] * s);
            *(uint2*)(Y + (size_t)gr * M + col0 + tc * 4) = pk.u;
        }
    }
}

// out[node,:] = Zadd[node,:] - dis[node] * sum_e Ssrc[col_e,:]  (+bias, relu, lsm)
// Ssrc rows are pre-scaled by dis at their producer, so no per-edge weight.
// If PRESCALE, the stored value is dis[node]*v (feeding the next propagation).
// Edge loop unrolled 8-deep: 8 scalar col loads then 8 independent gathers in
// flight per wave (latency-bound regime; round-1 showed VALUBusy 14%).
template <int C, bool RELU, bool BIAS, bool LSM, bool PRESCALE, typename TO>
__global__ __launch_bounds__(256) void prop_kernel(
        const int* __restrict__ row_start,
        const int* __restrict__ csr_col,
        const float* __restrict__ dis,
        const __half* __restrict__ Ssrc, int ld_src,
        const __half* __restrict__ Zadd, int ld_add,
        const float* __restrict__ bias,
        TO* __restrict__ out, int ld_out, int n) {
    constexpr int NPB = 256 / C;
    int g    = threadIdx.x / C;
    int lane = threadIdx.x % C;
    int node = blockIdx.x * NPB + g;
    if (node >= n) return;
    int s = row_start[node], e = row_start[node + 1];
    if (C == 64) {   // wave-uniform bounds -> scalar loads for col indices
        s = __builtin_amdgcn_readfirstlane(s);
        e = __builtin_amdgcn_readfirstlane(e);
    }
    float dn = dis[node];
    float acc = 0.0f;
    int i = s;
    for (; i + 8 <= e; i += 8) {
        int cc[8];
#pragma unroll
        for (int u = 0; u < 8; ++u) cc[u] = csr_col[i + u];
        float vv[8];
#pragma unroll
        for (int u = 0; u < 8; ++u) vv[u] = __half2float(Ssrc[(size_t)cc[u] * ld_src + lane]);
        acc += ((vv[0] + vv[1]) + (vv[2] + vv[3])) + ((vv[4] + vv[5]) + (vv[6] + vv[7]));
    }
    for (; i < e; ++i)
        acc += __half2float(Ssrc[(size_t)csr_col[i] * ld_src + lane]);

    float v = fmaf(-dn, acc, __half2float(Zadd[(size_t)node * ld_add + lane]));
    if (BIAS) v += bias[lane];
    if (RELU) v = fmaxf(v, 0.0f);
    if (LSM) {
        float m = v;
#pragma unroll
        for (int off = 16; off > 0; off >>= 1) m = fmaxf(m, __shfl_xor(m, off, 32));
        float ex = __expf(v - m);
        float sum = ex;
#pragma unroll
        for (int off = 16; off > 0; off >>= 1) sum += __shfl_xor(sum, off, 32);
        v = (v - m) - __logf(sum);
    }
    if (PRESCALE) v *= dn;
    if constexpr (sizeof(TO) == 2) {
        out[(size_t)node * ld_out + lane] = (TO)__float2half_rn(v);
    } else {
        out[(size_t)node * ld_out + lane] = v;
    }
}

extern "C" void kernel_launch(void* const* d_in, const int* in_sizes, int n_in,
                              void* d_out, int out_size, void* d_ws, size_t ws_size,
                              hipStream_t stream) {
    const float* x  = (const float*)d_in[0];
    const int*   ei = (const int*)d_in[1];
    const float* W1 = (const float*)d_in[2];
    const float* b1 = (const float*)d_in[3];
    const float* W2 = (const float*)d_in[4];
    const float* b2 = (const float*)d_in[5];
    float* out = (float*)d_out;

    const int* row = ei;
    const int* col = ei + NE;

    char* p = (char*)d_ws;
    auto alloc = [&](size_t bytes) {
        char* q = p;
        p += (bytes + 255) & ~(size_t)255;
        return q;
    };
    float*  deg       = (float*)alloc((size_t)NN * 4);
    float*  dis       = (float*)alloc((size_t)NN * 4);
    int*    row_start = (int*)alloc((size_t)(NN + 1) * 4);
    int*    gcur      = (int*)alloc((size_t)NBKT * 4);
    int*    partials  = (int*)alloc(512 * 4);
    int*    csr_col   = (int*)alloc((size_t)NE * 4);
    float*  A1        = (float*)alloc((size_t)IN_C * 4 * HID_C * 4);
    float*  A2        = (float*)alloc((size_t)HID_C * 4 * OUT_C * 4);
    __half* ZZ        = (__half*)alloc((size_t)NN * 256 * 2);  // layer1 Z; reused layer2
    __half* Sa        = (__half*)alloc((size_t)NN * 64 * 2);
    __half* Sb        = (__half*)alloc((size_t)NN * 64 * 2);
    __half* h         = (__half*)alloc((size_t)NN * 64 * 2);

    // Staging (7.2 MB) lives in ZZ, which is dead until matmul1 writes it.
    unsigned* staging = (unsigned*)ZZ;

    hipMemsetAsync(deg, 0, (size_t)NN * 4, stream);
    hipMemsetAsync(gcur, 0, (size_t)NBKT * 4, stream);
    deg_kernel<<<cdiv(NE, 256), 256, 0, stream>>>(row, deg, NE);
    dis_kernel<<<cdiv(NN, 256), 256, 0, stream>>>(deg, dis, NN);
    scan1_kernel<<<cdiv(NN, 256), 256, 0, stream>>>(deg, row_start, partials, NN);
    scan2_kernel<<<1, 512, 0, stream>>>(partials, cdiv(NN, 256));
    scan3_kernel<<<cdiv(NN, 256), 256, 0, stream>>>(row_start, partials, NN, NE);
    scatter_p1<<<cdiv(NE, EPB), 256, 0, stream>>>(row, col, gcur, staging, NE);
    scatter_p2<<<NBKT, 512, 0, stream>>>(row_start, gcur, staging, csr_col, NN);

    wtrans_kernel<<<cdiv(IN_C * 4 * HID_C, 256), 256, 0, stream>>>(W1, A1, IN_C, HID_C);
    wtrans_kernel<<<cdiv(HID_C * 4 * OUT_C, 256), 256, 0, stream>>>(W2, A2, HID_C, OUT_C);

    // Layer 1: ZZ[N,256] = x @ A1 (Z3 slice pre-scaled by dis), Horner props C=64.
    {
        dim3 g1(cdiv(NN, 64), 4);
        matmul64_kernel<float><<<g1, 256, 0, stream>>>(x, A1, ZZ, dis, NN, IN_C, 256, 3 * HID_C);
    }
    prop_kernel<64, false, false, false, true,  __half><<<cdiv(NN, 4), 256, 0, stream>>>(
        row_start, csr_col, dis, ZZ + 3 * 64, 256, ZZ + 2 * 64, 256, nullptr, Sa, 64, NN);
    prop_kernel<64, false, false, false, true,  __half><<<cdiv(NN, 4), 256, 0, stream>>>(
        row_start, csr_col, dis, Sa, 64, ZZ + 1 * 64, 256, nullptr, Sb, 64, NN);
    prop_kernel<64, true,  true,  false, false, __half><<<cdiv(NN, 4), 256, 0, stream>>>(
        row_start, csr_col, dis, Sb, 64, ZZ + 0, 256, b1, h, 64, NN);

    // Layer 2: ZZ[N,128] = h @ A2, Horner props C=32, fused log_softmax.
    {
        dim3 g2(cdiv(NN, 64), 2);
        matmul64_kernel<__half><<<g2, 256, 0, stream>>>(h, A2, ZZ, dis, NN, HID_C, 128, 3 * OUT_C);
    }
    prop_kernel<32, false, false, false, true,  __half><<<cdiv(NN, 8), 256, 0, stream>>>(
        row_start, csr_col, dis, ZZ + 3 * 32, 128, ZZ + 2 * 32, 128, nullptr, Sa, 32, NN);
    prop_kernel<32, false, false, false, true,  __half><<<cdiv(NN, 8), 256, 0, stream>>>(
        row_start, csr_col, dis, Sa, 32, ZZ + 1 * 32, 128, nullptr, Sb, 32, NN);
    prop_kernel<32, false, true,  true,  false, float><<<cdiv(NN, 8), 256, 0, stream>>>(
        row_start, csr_col, dis, Sb, 32, ZZ + 0, 128, b2, out, 32, NN);
}

// Round 12
// 569.581 us; speedup vs baseline: 1.3522x; 1.1330x over previous
//
#include <hip/hip_runtime.h>
#include <hip/hip_fp16.h>
#include <cstdint>
#include <cstddef>

static constexpr int NN    = 100000;
static constexpr int NE    = 1600000;
static constexpr int IN_C  = 128;
static constexpr int HID_C = 64;
static constexpr int OUT_C = 32;

// LDS-binned scatter geometry: coarse bucket = row>>10 (1024 rows/bucket).
static constexpr int NBKT = (NN + 1023) >> 10;   // 98
static constexpr int LCAP = 96;                  // LDS bin capacity
static constexpr int GCAP = 18432;               // global bucket cap
static constexpr int EPB  = 4096;                // edges per phase-A block

typedef _Float16 f16x8 __attribute__((ext_vector_type(8)));
typedef float    f32x4 __attribute__((ext_vector_type(4)));

static inline int cdiv(int a, int b) { return (a + b - 1) / b; }

__global__ void deg_kernel(const int* __restrict__ row, float* __restrict__ deg, int E) {
    int i = blockIdx.x * 256 + threadIdx.x;
    if (i < E) atomicAdd(&deg[row[i]], 1.0f);
}

__global__ void dis_kernel(const float* __restrict__ deg, float* __restrict__ dis, int n) {
    int i = blockIdx.x * 256 + threadIdx.x;
    if (i < n) {
        float d = deg[i];
        dis[i] = d > 0.0f ? rsqrtf(fmaxf(d, 1.0f)) : 0.0f;
    }
}

__global__ void scan1_kernel(const float* __restrict__ deg, int* __restrict__ row_start,
                             int* __restrict__ partials, int n) {
    __shared__ int tmp[256];
    int t = threadIdx.x;
    int i = blockIdx.x * 256 + t;
    int v = (i < n) ? (int)deg[i] : 0;
    tmp[t] = v;
    __syncthreads();
    for (int off = 1; off < 256; off <<= 1) {
        int add = (t >= off) ? tmp[t - off] : 0;
        __syncthreads();
        tmp[t] += add;
        __syncthreads();
    }
    if (i < n) row_start[i] = tmp[t] - v;
    if (t == 255) partials[blockIdx.x] = tmp[t];
}

__global__ void scan2_kernel(int* __restrict__ partials, int nparts) {
    __shared__ int tmp[512];
    int t = threadIdx.x;
    int v = (t < nparts) ? partials[t] : 0;
    tmp[t] = v;
    __syncthreads();
    for (int off = 1; off < 512; off <<= 1) {
        int add = (t >= off) ? tmp[t - off] : 0;
        __syncthreads();
        tmp[t] += add;
        __syncthreads();
    }
    if (t < nparts) partials[t] = tmp[t] - v;
}

__global__ void scan3_kernel(int* __restrict__ row_start, const int* __restrict__ partials,
                             int n, int total) {
    int i = blockIdx.x * 256 + threadIdx.x;
    if (i < n) row_start[i] += partials[blockIdx.x];
    if (i == 0) row_start[n] = total;
}

// Phase A: LDS-bin 4096 edges by row>>10, then per-bin global reservation +
// coalesced flush. Pack = ((row & 1023) << 17) | col.
__global__ __launch_bounds__(256) void scatter_p1(
        const int* __restrict__ row, const int* __restrict__ col,
        int* __restrict__ gcur, unsigned* __restrict__ staging, int E) {
    __shared__ unsigned bins[NBKT][LCAP];
    __shared__ int bcnt[NBKT];
    __shared__ int bbase[NBKT];
    int tid = threadIdx.x;
    for (int b = tid; b < NBKT; b += 256) bcnt[b] = 0;
    __syncthreads();
    int base = blockIdx.x * EPB;
#pragma unroll
    for (int rep = 0; rep < 4; ++rep) {
        int i = base + rep * 1024 + tid * 4;
        if (i < E) {
            int4 r4 = *(const int4*)(row + i);
            int4 c4 = *(const int4*)(col + i);
            int rr[4] = {r4.x, r4.y, r4.z, r4.w};
            int cc[4] = {c4.x, c4.y, c4.z, c4.w};
#pragma unroll
            for (int u = 0; u < 4; ++u) {
                int bin = rr[u] >> 10;
                unsigned pk = ((unsigned)(rr[u] & 1023) << 17) | (unsigned)cc[u];
                int pos = atomicAdd(&bcnt[bin], 1);
                if (pos < LCAP) {
                    bins[bin][pos] = pk;
                } else {
                    int gp = atomicAdd(&gcur[bin], 1);
                    if (gp < GCAP) staging[(size_t)bin * GCAP + gp] = pk;
                }
            }
        }
    }
    __syncthreads();
    if (tid < NBKT) {
        int cnt = min(bcnt[tid], LCAP);
        bbase[tid] = atomicAdd(&gcur[tid], cnt);
    }
    __syncthreads();
    int wv = tid >> 6, ln = tid & 63;
    for (int b = wv; b < NBKT; b += 4) {
        int cnt = min(bcnt[b], LCAP);
        int gb  = bbase[b];
        for (int j = ln; j < cnt; j += 64)
            staging[(size_t)b * GCAP + gb + j] = bins[b][j];
    }
}

// Phase B: one block per bucket; LDS cursors; csr writes land in the bucket's
// block-exclusive ~131KB L2-resident range.
__global__ __launch_bounds__(512) void scatter_p2(
        const int* __restrict__ row_start, const int* __restrict__ gcur,
        const unsigned* __restrict__ staging, int* __restrict__ csr_col, int n) {
    __shared__ int lcur[1024];
    int b = blockIdx.x;
    int r0 = b << 10;
    for (int t = threadIdx.x; t < 1024; t += 512) {
        int r = r0 + t;
        lcur[t] = (r < n) ? row_start[r] : 0;
    }
    __syncthreads();
    int cnt = min(gcur[b], GCAP);
    const unsigned* seg = staging + (size_t)b * GCAP;
    for (int j = threadIdx.x; j < cnt; j += 512) {
        unsigned u = seg[j];
        int lr = (int)(u >> 17);
        int c  = (int)(u & 0x1FFFF);
        int pos = atomicAdd(&lcur[lr], 1);
        csr_col[pos] = c;
    }
}

// A_T layout: AT[m][k] fp16 where m = kk*Cout + o, k = c.
// A0=W0-W2, A1=W1-3W3, A2=2W2, A3=4W3.
__global__ void wtrans_kernel(const float* __restrict__ W, __half* __restrict__ AT,
                              int Cin, int Cout) {
    int idx = blockIdx.x * 256 + threadIdx.x;
    int total = Cin * 4 * Cout;
    if (idx >= total) return;
    int o  = idx % Cout;
    int kk = (idx / Cout) & 3;
    int c  = idx / (4 * Cout);
    size_t s = (size_t)Cin * Cout;
    float v;
    if (kk == 0)      v = W[0 * s + (size_t)c * Cout + o] - W[2 * s + (size_t)c * Cout + o];
    else if (kk == 1) v = W[1 * s + (size_t)c * Cout + o] - 3.0f * W[3 * s + (size_t)c * Cout + o];
    else if (kk == 2) v = 2.0f * W[2 * s + (size_t)c * Cout + o];
    else              v = 4.0f * W[3 * s + (size_t)c * Cout + o];
    AT[(size_t)(kk * Cout + o) * Cin + c] = __float2half_rn(v);
}

// Y[N,MD] = X[N,KD] @ A[KD,MD] via mfma_f32_16x16x32_f16 (fp32 accum).
// BM=128 rows/block, 8 waves (2 m x 4 n), BN = full MD so X is read once.
// X staged to LDS fp16 [128][KD+8] (pad -> 2-way banks, free). A_T[m][k] fp16
// read as 16B global loads (L2-resident, 64/16 KB total). Cols >= C3B
// pre-scaled by dis[row]. Fragment mapping per learn_hip m89 (verified):
//   a[j]=X[l&15][ks*32+(l>>4)*8+j], b[j]=A[k][col=l&15], D: row=(l>>4)*4+r, col=l&15.
template <typename TI, int KD, int MD, int C3B>
__global__ __launch_bounds__(512) void matmul_mfma(
        const TI* __restrict__ X, const __half* __restrict__ AT,
        __half* __restrict__ Y, const float* __restrict__ dis, int n) {
    constexpr int PAD = KD + 8;
    constexpr int NT  = MD / 64;     // 16-col tiles per wave
    __shared__ _Float16 xs[128][PAD];
    int tid  = threadIdx.x;
    int row0 = blockIdx.x * 128;
    if constexpr (sizeof(TI) == 4) {
        constexpr int CPR = KD / 4;                    // float4 chunks per row
#pragma unroll
        for (int it = 0; it < (128 * CPR) / 512; ++it) {
            int j = tid + it * 512;
            int r = j / CPR, q = j % CPR;
            int gr = row0 + r;
            float4 v = make_float4(0.f, 0.f, 0.f, 0.f);
            if (gr < n) v = *(const float4*)((const float*)X + (size_t)gr * KD + q * 4);
            *(__half2*)&xs[r][q * 4]     = __floats2half2_rn(v.x, v.y);
            *(__half2*)&xs[r][q * 4 + 2] = __floats2half2_rn(v.z, v.w);
        }
    } else {
        constexpr int CPR = KD / 8;                    // 16B chunks per row
#pragma unroll
        for (int it = 0; it < (128 * CPR) / 512; ++it) {
            int j = tid + it * 512;
            int r = j / CPR, q = j % CPR;
            int gr = row0 + r;
            uint4 v = make_uint4(0, 0, 0, 0);
            if (gr < n) v = *(const uint4*)((const __half*)X + (size_t)gr * KD + q * 8);
            *(uint4*)&xs[r][q * 8] = v;
        }
    }
    __syncthreads();

    int w = tid >> 6, l = tid & 63;
    int l15 = l & 15, lg = l >> 4;
    int mrb  = (w >> 2) * 64;          // wave row base within block
    int colb = (w & 3) * (MD / 4);     // wave col base

    f32x4 acc[4][NT] = {};
#pragma unroll
    for (int ks = 0; ks < KD / 32; ++ks) {
        f16x8 a[4], b[NT];
#pragma unroll
        for (int mt = 0; mt < 4; ++mt)
            a[mt] = *(const f16x8*)&xs[mrb + mt * 16 + l15][ks * 32 + lg * 8];
#pragma unroll
        for (int nt = 0; nt < NT; ++nt)
            b[nt] = *(const f16x8*)((const _Float16*)AT +
                     (size_t)(colb + nt * 16 + l15) * KD + ks * 32 + lg * 8);
#pragma unroll
        for (int mt = 0; mt < 4; ++mt)
#pragma unroll
            for (int nt = 0; nt < NT; ++nt)
                acc[mt][nt] = __builtin_amdgcn_mfma_f32_16x16x32_f16(
                                  a[mt], b[nt], acc[mt][nt], 0, 0, 0);
    }

#pragma unroll
    for (int mt = 0; mt < 4; ++mt) {
#pragma unroll
        for (int r = 0; r < 4; ++r) {
            int row = row0 + mrb + mt * 16 + lg * 4 + r;
            if (row < n) {
                float dv = dis[row];
#pragma unroll
                for (int nt = 0; nt < NT; ++nt) {
                    bool z3 = (colb + nt * 16) >= C3B;   // 16-aligned -> tile-uniform
                    int col = colb + nt * 16 + l15;
                    float s = z3 ? dv : 1.0f;
                    Y[(size_t)row * MD + col] = __float2half_rn(acc[mt][nt][r] * s);
                }
            }
        }
    }
}

// out[node,:] = Zadd[node,:] - dis[node] * sum_e Ssrc[col_e,:]  (+bias, relu, lsm)
template <int C, bool RELU, bool BIAS, bool LSM, bool PRESCALE, typename TO>
__global__ __launch_bounds__(256) void prop_kernel(
        const int* __restrict__ row_start,
        const int* __restrict__ csr_col,
        const float* __restrict__ dis,
        const __half* __restrict__ Ssrc, int ld_src,
        const __half* __restrict__ Zadd, int ld_add,
        const float* __restrict__ bias,
        TO* __restrict__ out, int ld_out, int n) {
    constexpr int NPB = 256 / C;
    int g    = threadIdx.x / C;
    int lane = threadIdx.x % C;
    int node = blockIdx.x * NPB + g;
    if (node >= n) return;
    int s = row_start[node], e = row_start[node + 1];
    if (C == 64) {
        s = __builtin_amdgcn_readfirstlane(s);
        e = __builtin_amdgcn_readfirstlane(e);
    }
    float dn = dis[node];
    float acc = 0.0f;
    int i = s;
    for (; i + 8 <= e; i += 8) {
        int cc[8];
#pragma unroll
        for (int u = 0; u < 8; ++u) cc[u] = csr_col[i + u];
        float vv[8];
#pragma unroll
        for (int u = 0; u < 8; ++u) vv[u] = __half2float(Ssrc[(size_t)cc[u] * ld_src + lane]);
        acc += ((vv[0] + vv[1]) + (vv[2] + vv[3])) + ((vv[4] + vv[5]) + (vv[6] + vv[7]));
    }
    for (; i < e; ++i)
        acc += __half2float(Ssrc[(size_t)csr_col[i] * ld_src + lane]);

    float v = fmaf(-dn, acc, __half2float(Zadd[(size_t)node * ld_add + lane]));
    if (BIAS) v += bias[lane];
    if (RELU) v = fmaxf(v, 0.0f);
    if (LSM) {
        float m = v;
#pragma unroll
        for (int off = 16; off > 0; off >>= 1) m = fmaxf(m, __shfl_xor(m, off, 32));
        float ex = __expf(v - m);
        float sum = ex;
#pragma unroll
        for (int off = 16; off > 0; off >>= 1) sum += __shfl_xor(sum, off, 32);
        v = (v - m) - __logf(sum);
    }
    if (PRESCALE) v *= dn;
    if constexpr (sizeof(TO) == 2) {
        out[(size_t)node * ld_out + lane] = (TO)__float2half_rn(v);
    } else {
        out[(size_t)node * ld_out + lane] = v;
    }
}

extern "C" void kernel_launch(void* const* d_in, const int* in_sizes, int n_in,
                              void* d_out, int out_size, void* d_ws, size_t ws_size,
                              hipStream_t stream) {
    const float* x  = (const float*)d_in[0];
    const int*   ei = (const int*)d_in[1];
    const float* W1 = (const float*)d_in[2];
    const float* b1 = (const float*)d_in[3];
    const float* W2 = (const float*)d_in[4];
    const float* b2 = (const float*)d_in[5];
    float* out = (float*)d_out;

    const int* row = ei;
    const int* col = ei + NE;

    char* p = (char*)d_ws;
    auto alloc = [&](size_t bytes) {
        char* q = p;
        p += (bytes + 255) & ~(size_t)255;
        return q;
    };
    float*  deg       = (float*)alloc((size_t)NN * 4);
    float*  dis       = (float*)alloc((size_t)NN * 4);
    int*    row_start = (int*)alloc((size_t)(NN + 1) * 4);
    int*    gcur      = (int*)alloc((size_t)NBKT * 4);
    int*    partials  = (int*)alloc(512 * 4);
    int*    csr_col   = (int*)alloc((size_t)NE * 4);
    __half* A1h       = (__half*)alloc((size_t)4 * HID_C * IN_C * 2);
    __half* A2h       = (__half*)alloc((size_t)4 * OUT_C * HID_C * 2);
    __half* ZZ        = (__half*)alloc((size_t)NN * 256 * 2);  // layer1 Z; reused layer2
    __half* Sa        = (__half*)alloc((size_t)NN * 64 * 2);
    __half* Sb        = (__half*)alloc((size_t)NN * 64 * 2);
    __half* h         = (__half*)alloc((size_t)NN * 64 * 2);

    // Scatter staging (7.2 MB) lives in ZZ, dead until matmul1 writes it.
    unsigned* staging = (unsigned*)ZZ;

    hipMemsetAsync(deg, 0, (size_t)NN * 4, stream);
    hipMemsetAsync(gcur, 0, (size_t)NBKT * 4, stream);
    deg_kernel<<<cdiv(NE, 256), 256, 0, stream>>>(row, deg, NE);
    dis_kernel<<<cdiv(NN, 256), 256, 0, stream>>>(deg, dis, NN);
    scan1_kernel<<<cdiv(NN, 256), 256, 0, stream>>>(deg, row_start, partials, NN);
    scan2_kernel<<<1, 512, 0, stream>>>(partials, cdiv(NN, 256));
    scan3_kernel<<<cdiv(NN, 256), 256, 0, stream>>>(row_start, partials, NN, NE);
    scatter_p1<<<cdiv(NE, EPB), 256, 0, stream>>>(row, col, gcur, staging, NE);
    scatter_p2<<<NBKT, 512, 0, stream>>>(row_start, gcur, staging, csr_col, NN);

    wtrans_kernel<<<cdiv(IN_C * 4 * HID_C, 256), 256, 0, stream>>>(W1, A1h, IN_C, HID_C);
    wtrans_kernel<<<cdiv(HID_C * 4 * OUT_C, 256), 256, 0, stream>>>(W2, A2h, HID_C, OUT_C);

    // Layer 1: ZZ[N,256] = x @ A1 (Z3 slice pre-scaled by dis), Horner props C=64.
    matmul_mfma<float, 128, 256, 3 * HID_C><<<cdiv(NN, 128), 512, 0, stream>>>(
        x, A1h, ZZ, dis, NN);
    prop_kernel<64, false, false, false, true,  __half><<<cdiv(NN, 4), 256, 0, stream>>>(
        row_start, csr_col, dis, ZZ + 3 * 64, 256, ZZ + 2 * 64, 256, nullptr, Sa, 64, NN);
    prop_kernel<64, false, false, false, true,  __half><<<cdiv(NN, 4), 256, 0, stream>>>(
        row_start, csr_col, dis, Sa, 64, ZZ + 1 * 64, 256, nullptr, Sb, 64, NN);
    prop_kernel<64, true,  true,  false, false, __half><<<cdiv(NN, 4), 256, 0, stream>>>(
        row_start, csr_col, dis, Sb, 64, ZZ + 0, 256, b1, h, 64, NN);

    // Layer 2: ZZ[N,128] = h @ A2, Horner props C=32, fused log_softmax.
    matmul_mfma<__half, 64, 128, 3 * OUT_C><<<cdiv(NN, 128), 512, 0, stream>>>(
        h, A2h, ZZ, dis, NN);
    prop_kernel<32, false, false, false, true,  __half><<<cdiv(NN, 8), 256, 0, stream>>>(
        row_start, csr_col, dis, ZZ + 3 * 32, 128, ZZ + 2 * 32, 128, nullptr, Sa, 32, NN);
    prop_kernel<32, false, false, false, true,  __half><<<cdiv(NN, 8), 256, 0, stream>>>(
        row_start, csr_col, dis, Sa, 32, ZZ + 1 * 32, 128, nullptr, Sb, 32, NN);
    prop_kernel<32, false, true,  true,  false, float><<<cdiv(NN, 8), 256, 0, stream>>>(
        row_start, csr_col, dis, Sb, 32, ZZ + 0, 128, b2, out, 32, NN);
}

// Round 14
// 488.156 us; speedup vs baseline: 1.5778x; 1.1668x over previous
//
#include <hip/hip_runtime.h>
#include <hip/hip_fp16.h>
#include <cstdint>
#include <cstddef>

static constexpr int NN    = 100000;
static constexpr int NE    = 1600000;
static constexpr int IN_C  = 128;
static constexpr int HID_C = 64;
static constexpr int OUT_C = 32;

// LDS-binned scatter geometry: coarse bucket = row>>10 (1024 rows/bucket).
static constexpr int NBKT = (NN + 1023) >> 10;   // 98
static constexpr int LCAP = 96;                  // LDS bin capacity
static constexpr int GCAP = 18432;               // global bucket cap
static constexpr int EPB  = 4096;                // edges per phase-A block

typedef _Float16 f16x8 __attribute__((ext_vector_type(8)));
typedef float    f32x4 __attribute__((ext_vector_type(4)));

static inline int cdiv(int a, int b) { return (a + b - 1) / b; }

__global__ void scan1_kernel(const float* __restrict__ deg, int* __restrict__ row_start,
                             int* __restrict__ partials, int n) {
    __shared__ int tmp[256];
    int t = threadIdx.x;
    int i = blockIdx.x * 256 + t;
    int v = (i < n) ? (int)deg[i] : 0;
    tmp[t] = v;
    __syncthreads();
    for (int off = 1; off < 256; off <<= 1) {
        int add = (t >= off) ? tmp[t - off] : 0;
        __syncthreads();
        tmp[t] += add;
        __syncthreads();
    }
    if (i < n) row_start[i] = tmp[t] - v;
    if (t == 255) partials[blockIdx.x] = tmp[t];
}

__global__ void scan2_kernel(int* __restrict__ partials, int nparts) {
    __shared__ int tmp[512];
    int t = threadIdx.x;
    int v = (t < nparts) ? partials[t] : 0;
    tmp[t] = v;
    __syncthreads();
    for (int off = 1; off < 512; off <<= 1) {
        int add = (t >= off) ? tmp[t - off] : 0;
        __syncthreads();
        tmp[t] += add;
        __syncthreads();
    }
    if (t < nparts) partials[t] = tmp[t] - v;
}

__global__ void scan3_kernel(int* __restrict__ row_start, const int* __restrict__ partials,
                             int n, int total) {
    int i = blockIdx.x * 256 + threadIdx.x;
    if (i < n) row_start[i] += partials[blockIdx.x];
    if (i == 0) row_start[n] = total;
}

// Phase A: LDS-bin 4096 edges by row>>10, then per-bin global reservation +
// coalesced flush. Pack = ((row & 1023) << 17) | col. Runs FIRST (needs no deg).
// Invariant: staging[b*GCAP .. b*GCAP+gcur[b]) is fully populated (every
// reservation -- LDS flush or overflow fallback -- writes its slot).
__global__ __launch_bounds__(256) void scatter_p1(
        const int* __restrict__ row, const int* __restrict__ col,
        int* __restrict__ gcur, unsigned* __restrict__ staging, int E) {
    __shared__ unsigned bins[NBKT][LCAP];
    __shared__ int bcnt[NBKT];
    __shared__ int bbase[NBKT];
    int tid = threadIdx.x;
    for (int b = tid; b < NBKT; b += 256) bcnt[b] = 0;
    __syncthreads();
    int base = blockIdx.x * EPB;
#pragma unroll
    for (int rep = 0; rep < 4; ++rep) {
        int i = base + rep * 1024 + tid * 4;
        if (i < E) {
            int4 r4 = *(const int4*)(row + i);
            int4 c4 = *(const int4*)(col + i);
            int rr[4] = {r4.x, r4.y, r4.z, r4.w};
            int cc[4] = {c4.x, c4.y, c4.z, c4.w};
#pragma unroll
            for (int u = 0; u < 4; ++u) {
                int bin = rr[u] >> 10;
                unsigned pk = ((unsigned)(rr[u] & 1023) << 17) | (unsigned)cc[u];
                int pos = atomicAdd(&bcnt[bin], 1);
                if (pos < LCAP) {
                    bins[bin][pos] = pk;
                } else {
                    int gp = atomicAdd(&gcur[bin], 1);
                    if (gp < GCAP) staging[(size_t)bin * GCAP + gp] = pk;
                }
            }
        }
    }
    __syncthreads();
    if (tid < NBKT) {
        int cnt = min(bcnt[tid], LCAP);
        bbase[tid] = atomicAdd(&gcur[tid], cnt);
    }
    __syncthreads();
    int wv = tid >> 6, ln = tid & 63;
    for (int b = wv; b < NBKT; b += 4) {
        int cnt = min(bcnt[b], LCAP);
        int gb  = bbase[b];
        for (int j = ln; j < cnt; j += 64)
            staging[(size_t)b * GCAP + gb + j] = bins[b][j];
    }
}

// Degree histogram from staged buckets: LDS atomics + dense coalesced writes
// of deg AND dis (dis folded in -- elementwise function of deg). Replaces the
// random-global-atomic deg kernel (was 84us / 50MB writeback).
__global__ __launch_bounds__(512) void deg_from_staging(
        const int* __restrict__ gcur, const unsigned* __restrict__ staging,
        float* __restrict__ deg, float* __restrict__ dis, int n) {
    __shared__ int hist[1024];
    for (int t = threadIdx.x; t < 1024; t += 512) hist[t] = 0;
    __syncthreads();
    int b = blockIdx.x;
    int cnt = min(gcur[b], GCAP);
    const unsigned* seg = staging + (size_t)b * GCAP;
    for (int j = threadIdx.x; j < cnt; j += 512)
        atomicAdd(&hist[seg[j] >> 17], 1);
    __syncthreads();
    int r0 = b << 10;
    for (int t = threadIdx.x; t < 1024; t += 512) {
        int r = r0 + t;
        if (r < n) {
            float d = (float)hist[t];
            deg[r] = d;
            dis[r] = d > 0.0f ? rsqrtf(fmaxf(d, 1.0f)) : 0.0f;
        }
    }
}

// Phase B: one block per bucket; LDS cursors; csr writes land in the bucket's
// block-exclusive ~131KB L2-resident range.
__global__ __launch_bounds__(512) void scatter_p2(
        const int* __restrict__ row_start, const int* __restrict__ gcur,
        const unsigned* __restrict__ staging, int* __restrict__ csr_col, int n) {
    __shared__ int lcur[1024];
    int b = blockIdx.x;
    int r0 = b << 10;
    for (int t = threadIdx.x; t < 1024; t += 512) {
        int r = r0 + t;
        lcur[t] = (r < n) ? row_start[r] : 0;
    }
    __syncthreads();
    int cnt = min(gcur[b], GCAP);
    const unsigned* seg = staging + (size_t)b * GCAP;
    for (int j = threadIdx.x; j < cnt; j += 512) {
        unsigned u = seg[j];
        int lr = (int)(u >> 17);
        int c  = (int)(u & 0x1FFFF);
        int pos = atomicAdd(&lcur[lr], 1);
        csr_col[pos] = c;
    }
}

// A_T layout: AT[m][k] fp16 where m = kk*Cout + o, k = c.
// A0=W0-W2, A1=W1-3W3, A2=2W2, A3=4W3.
__global__ void wtrans_kernel(const float* __restrict__ W, __half* __restrict__ AT,
                              int Cin, int Cout) {
    int idx = blockIdx.x * 256 + threadIdx.x;
    int total = Cin * 4 * Cout;
    if (idx >= total) return;
    int o  = idx % Cout;
    int kk = (idx / Cout) & 3;
    int c  = idx / (4 * Cout);
    size_t s = (size_t)Cin * Cout;
    float v;
    if (kk == 0)      v = W[0 * s + (size_t)c * Cout + o] - W[2 * s + (size_t)c * Cout + o];
    else if (kk == 1) v = W[1 * s + (size_t)c * Cout + o] - 3.0f * W[3 * s + (size_t)c * Cout + o];
    else if (kk == 2) v = 2.0f * W[2 * s + (size_t)c * Cout + o];
    else              v = 4.0f * W[3 * s + (size_t)c * Cout + o];
    AT[(size_t)(kk * Cout + o) * Cin + c] = __float2half_rn(v);
}

// Y[N,MD] = X[N,KD] @ A[KD,MD] via mfma_f32_16x16x32_f16 (fp32 accum).
// BM=128 rows/block, 8 waves (2 m x 4 n), BN = full MD so X is read once.
// Fragment mapping per learn_hip m89 (verified round 12: absmax 0.0625).
template <typename TI, int KD, int MD, int C3B>
__global__ __launch_bounds__(512) void matmul_mfma(
        const TI* __restrict__ X, const __half* __restrict__ AT,
        __half* __restrict__ Y, const float* __restrict__ dis, int n) {
    constexpr int PAD = KD + 8;
    constexpr int NT  = MD / 64;     // 16-col tiles per wave
    __shared__ _Float16 xs[128][PAD];
    int tid  = threadIdx.x;
    int row0 = blockIdx.x * 128;
    if constexpr (sizeof(TI) == 4) {
        constexpr int CPR = KD / 4;                    // float4 chunks per row
#pragma unroll
        for (int it = 0; it < (128 * CPR) / 512; ++it) {
            int j = tid + it * 512;
            int r = j / CPR, q = j % CPR;
            int gr = row0 + r;
            float4 v = make_float4(0.f, 0.f, 0.f, 0.f);
            if (gr < n) v = *(const float4*)((const float*)X + (size_t)gr * KD + q * 4);
            *(__half2*)&xs[r][q * 4]     = __floats2half2_rn(v.x, v.y);
            *(__half2*)&xs[r][q * 4 + 2] = __floats2half2_rn(v.z, v.w);
        }
    } else {
        constexpr int CPR = KD / 8;                    // 16B chunks per row
#pragma unroll
        for (int it = 0; it < (128 * CPR) / 512; ++it) {
            int j = tid + it * 512;
            int r = j / CPR, q = j % CPR;
            int gr = row0 + r;
            uint4 v = make_uint4(0, 0, 0, 0);
            if (gr < n) v = *(const uint4*)((const __half*)X + (size_t)gr * KD + q * 8);
            *(uint4*)&xs[r][q * 8] = v;
        }
    }
    __syncthreads();

    int w = tid >> 6, l = tid & 63;
    int l15 = l & 15, lg = l >> 4;
    int mrb  = (w >> 2) * 64;          // wave row base within block
    int colb = (w & 3) * (MD / 4);     // wave col base

    f32x4 acc[4][NT] = {};
#pragma unroll
    for (int ks = 0; ks < KD / 32; ++ks) {
        f16x8 a[4], b[NT];
#pragma unroll
        for (int mt = 0; mt < 4; ++mt)
            a[mt] = *(const f16x8*)&xs[mrb + mt * 16 + l15][ks * 32 + lg * 8];
#pragma unroll
        for (int nt = 0; nt < NT; ++nt)
            b[nt] = *(const f16x8*)((const _Float16*)AT +
                     (size_t)(colb + nt * 16 + l15) * KD + ks * 32 + lg * 8);
#pragma unroll
        for (int mt = 0; mt < 4; ++mt)
#pragma unroll
            for (int nt = 0; nt < NT; ++nt)
                acc[mt][nt] = __builtin_amdgcn_mfma_f32_16x16x32_f16(
                                  a[mt], b[nt], acc[mt][nt], 0, 0, 0);
    }

#pragma unroll
    for (int mt = 0; mt < 4; ++mt) {
#pragma unroll
        for (int r = 0; r < 4; ++r) {
            int row = row0 + mrb + mt * 16 + lg * 4 + r;
            if (row < n) {
                float dv = dis[row];
#pragma unroll
                for (int nt = 0; nt < NT; ++nt) {
                    bool z3 = (colb + nt * 16) >= C3B;   // 16-aligned -> tile-uniform
                    int col = colb + nt * 16 + l15;
                    float s = z3 ? dv : 1.0f;
                    Y[(size_t)row * MD + col] = __float2half_rn(acc[mt][nt][r] * s);
                }
            }
        }
    }
}

// out[node,:] = Zadd[node,:] - dis[node] * sum_e Ssrc[col_e,:]  (+bias, relu, lsm)
template <int C, bool RELU, bool BIAS, bool LSM, bool PRESCALE, typename TO>
__global__ __launch_bounds__(256) void prop_kernel(
        const int* __restrict__ row_start,
        const int* __restrict__ csr_col,
        const float* __restrict__ dis,
        const __half* __restrict__ Ssrc, int ld_src,
        const __half* __restrict__ Zadd, int ld_add,
        const float* __restrict__ bias,
        TO* __restrict__ out, int ld_out, int n) {
    constexpr int NPB = 256 / C;
    int g    = threadIdx.x / C;
    int lane = threadIdx.x % C;
    int node = blockIdx.x * NPB + g;
    if (node >= n) return;
    int s = row_start[node], e = row_start[node + 1];
    if (C == 64) {
        s = __builtin_amdgcn_readfirstlane(s);
        e = __builtin_amdgcn_readfirstlane(e);
    }
    float dn = dis[node];
    float acc = 0.0f;
    int i = s;
    for (; i + 8 <= e; i += 8) {
        int cc[8];
#pragma unroll
        for (int u = 0; u < 8; ++u) cc[u] = csr_col[i + u];
        float vv[8];
#pragma unroll
        for (int u = 0; u < 8; ++u) vv[u] = __half2float(Ssrc[(size_t)cc[u] * ld_src + lane]);
        acc += ((vv[0] + vv[1]) + (vv[2] + vv[3])) + ((vv[4] + vv[5]) + (vv[6] + vv[7]));
    }
    for (; i < e; ++i)
        acc += __half2float(Ssrc[(size_t)csr_col[i] * ld_src + lane]);

    float v = fmaf(-dn, acc, __half2float(Zadd[(size_t)node * ld_add + lane]));
    if (BIAS) v += bias[lane];
    if (RELU) v = fmaxf(v, 0.0f);
    if (LSM) {
        float m = v;
#pragma unroll
        for (int off = 16; off > 0; off >>= 1) m = fmaxf(m, __shfl_xor(m, off, 32));
        float ex = __expf(v - m);
        float sum = ex;
#pragma unroll
        for (int off = 16; off > 0; off >>= 1) sum += __shfl_xor(sum, off, 32);
        v = (v - m) - __logf(sum);
    }
    if (PRESCALE) v *= dn;
    if constexpr (sizeof(TO) == 2) {
        out[(size_t)node * ld_out + lane] = (TO)__float2half_rn(v);
    } else {
        out[(size_t)node * ld_out + lane] = v;
    }
}

extern "C" void kernel_launch(void* const* d_in, const int* in_sizes, int n_in,
                              void* d_out, int out_size, void* d_ws, size_t ws_size,
                              hipStream_t stream) {
    const float* x  = (const float*)d_in[0];
    const int*   ei = (const int*)d_in[1];
    const float* W1 = (const float*)d_in[2];
    const float* b1 = (const float*)d_in[3];
    const float* W2 = (const float*)d_in[4];
    const float* b2 = (const float*)d_in[5];
    float* out = (float*)d_out;

    const int* row = ei;
    const int* col = ei + NE;

    char* p = (char*)d_ws;
    auto alloc = [&](size_t bytes) {
        char* q = p;
        p += (bytes + 255) & ~(size_t)255;
        return q;
    };
    float*  deg       = (float*)alloc((size_t)NN * 4);
    float*  dis       = (float*)alloc((size_t)NN * 4);
    int*    row_start = (int*)alloc((size_t)(NN + 1) * 4);
    int*    gcur      = (int*)alloc((size_t)NBKT * 4);
    int*    partials  = (int*)alloc(512 * 4);
    int*    csr_col   = (int*)alloc((size_t)NE * 4);
    __half* A1h       = (__half*)alloc((size_t)4 * HID_C * IN_C * 2);
    __half* A2h       = (__half*)alloc((size_t)4 * OUT_C * HID_C * 2);
    __half* ZZ        = (__half*)alloc((size_t)NN * 256 * 2);  // layer1 Z; reused layer2
    __half* Sa        = (__half*)alloc((size_t)NN * 64 * 2);
    __half* Sb        = (__half*)alloc((size_t)NN * 64 * 2);
    __half* h         = (__half*)alloc((size_t)NN * 64 * 2);

    // Scatter staging (7.2 MB) lives in ZZ, dead until matmul1 writes it.
    unsigned* staging = (unsigned*)ZZ;

    hipMemsetAsync(gcur, 0, (size_t)NBKT * 4, stream);
    scatter_p1<<<cdiv(NE, EPB), 256, 0, stream>>>(row, col, gcur, staging, NE);
    deg_from_staging<<<NBKT, 512, 0, stream>>>(gcur, staging, deg, dis, NN);
    scan1_kernel<<<cdiv(NN, 256), 256, 0, stream>>>(deg, row_start, partials, NN);
    scan2_kernel<<<1, 512, 0, stream>>>(partials, cdiv(NN, 256));
    scan3_kernel<<<cdiv(NN, 256), 256, 0, stream>>>(row_start, partials, NN, NE);
    scatter_p2<<<NBKT, 512, 0, stream>>>(row_start, gcur, staging, csr_col, NN);

    wtrans_kernel<<<cdiv(IN_C * 4 * HID_C, 256), 256, 0, stream>>>(W1, A1h, IN_C, HID_C);
    wtrans_kernel<<<cdiv(HID_C * 4 * OUT_C, 256), 256, 0, stream>>>(W2, A2h, HID_C, OUT_C);

    // Layer 1: ZZ[N,256] = x @ A1 (Z3 slice pre-scaled by dis), Horner props C=64.
    matmul_mfma<float, 128, 256, 3 * HID_C><<<cdiv(NN, 128), 512, 0, stream>>>(
        x, A1h, ZZ, dis, NN);
    prop_kernel<64, false, false, false, true,  __half><<<cdiv(NN, 4), 256, 0, stream>>>(
        row_start, csr_col, dis, ZZ + 3 * 64, 256, ZZ + 2 * 64, 256, nullptr, Sa, 64, NN);
    prop_kernel<64, false, false, false, true,  __half><<<cdiv(NN, 4), 256, 0, stream>>>(
        row_start, csr_col, dis, Sa, 64, ZZ + 1 * 64, 256, nullptr, Sb, 64, NN);
    prop_kernel<64, true,  true,  false, false, __half><<<cdiv(NN, 4), 256, 0, stream>>>(
        row_start, csr_col, dis, Sb, 64, ZZ + 0, 256, b1, h, 64, NN);

    // Layer 2: ZZ[N,128] = h @ A2, Horner props C=32, fused log_softmax.
    matmul_mfma<__half, 64, 128, 3 * OUT_C><<<cdiv(NN, 128), 512, 0, stream>>>(
        h, A2h, ZZ, dis, NN);
    prop_kernel<32, false, false, false, true,  __half><<<cdiv(NN, 8), 256, 0, stream>>>(
        row_start, csr_col, dis, ZZ + 3 * 32, 128, ZZ + 2 * 32, 128, nullptr, Sa, 32, NN);
    prop_kernel<32, false, false, false, true,  __half><<<cdiv(NN, 8), 256, 0, stream>>>(
        row_start, csr_col, dis, Sa, 32, ZZ + 1 * 32, 128, nullptr, Sb, 32, NN);
    prop_kernel<32, false, true,  true,  false, float><<<cdiv(NN, 8), 256, 0, stream>>>(
        row_start, csr_col, dis, Sb, 32, ZZ + 0, 128, b2, out, 32, NN);
}